// Round 6
// baseline (2065.579 us; speedup 1.0000x reference)
//
#include <hip/hip_runtime.h>
#include <hip/hip_bf16.h>
#include <math.h>

// ---------------------------------------------------------------------------
// helpers
// ---------------------------------------------------------------------------
typedef __bf16 v8bf __attribute__((ext_vector_type(8)));
typedef float  v4f  __attribute__((ext_vector_type(4)));
typedef unsigned short v8us __attribute__((ext_vector_type(8)));

__device__ __forceinline__ unsigned short f2bfu(float f) {
    unsigned u = __builtin_bit_cast(unsigned, f);
    unsigned r = (u + 0x7fffu + ((u >> 16) & 1u)) >> 16;
    return (unsigned short)r;
}
__device__ __forceinline__ float bf2f(unsigned short u) {
    unsigned x = ((unsigned)u) << 16;
    return __builtin_bit_cast(float, x);
}

#define GLDS16(g, s)                                                        \
    __builtin_amdgcn_global_load_lds(                                       \
        (const __attribute__((address_space(1))) void*)(g),                 \
        (__attribute__((address_space(3))) void*)(s), 16, 0, 0)

// ---------------------------------------------------------------------------
// bf16 MFMA GEMM, REGISTER-DIRECT (no LDS, no barriers).
// C[M,N] = A[M,K] * B[N,K]^T + bias (+res fp32) (+relu)
// A row remap: r -> A + (r/rpbA)*bstrideA + (r%rpbA)*ldA   (conv-as-GEMM)
// Outputs: Cf (fp32) and/or Cb (bf16), ld ldC; cols >= ctcol0 (Ct!=null) go
// TRANSPOSED to Ct[(row>>10)<<20 + (col-ctcol0)*1024 + (row&1023)] (attn V^T).
// Tile 128(M)x64(N), 4 waves in 2x2; each wave computes 64x32 and loads its
// own MFMA fragments straight from global: per BK=32 chunk, 4 A-frag + 2
// B-frag global_load_dwordx4 per lane (16B contiguous each). Register
// double-buffered: issue chunk k+1 loads, MFMA chunk k, rotate. The compiler
// waits only on consumed registers -> load latency overlaps MFMA + other
// waves (no vmcnt(0) barrier drain, the R3-R5 stall).
// XCD m-slab swizzle for L2 locality.
// ---------------------------------------------------------------------------
__global__ __launch_bounds__(256) void gemm_mfma_k(
    const __hip_bfloat16* __restrict__ A, int rpbA, long long bstrideA, int ldA,
    const __hip_bfloat16* __restrict__ B,
    const float* __restrict__ bias,
    const float* __restrict__ res,
    float* __restrict__ Cf,
    __hip_bfloat16* __restrict__ Cb,
    unsigned short* __restrict__ Ct, int ctcol0,
    int M, int N, int K, int ldC, int relu)
{
    const int t  = threadIdx.x;
    const int w  = t >> 6;
    const int l  = t & 63;

    int bx = blockIdx.x, by = blockIdx.y;
    {
        int nbx = gridDim.x;
        int nb  = nbx * gridDim.y;
        if ((nb & 7) == 0) {
            int bid = by * nbx + bx;
            int nid = (bid & 7) * (nb >> 3) + (bid >> 3);
            by = nid / nbx;
            bx = nid - by * nbx;
        }
    }
    const int m0 = by * 128;
    const int n0 = bx * 64;
    const int r16 = l & 15;
    const int qb  = l >> 4;          // 0..3: k-subchunk (8 bf16 = 16B)
    const int wm = w >> 1, wn = w & 1;  // wave covers rows 64*wm.., cols 32*wn..

    // per-lane fragment pointers (A fragment: row = tile_base + (l&15),
    // k = (l>>4)*8 -> one contiguous 16B load per lane)
    const __hip_bfloat16* pa[4];
#pragma unroll
    for (int i = 0; i < 4; i++) {
        int arow = m0 + 64 * wm + 16 * i + r16;
        pa[i] = A + (long long)(arow / rpbA) * bstrideA
                  + (long long)(arow % rpbA) * ldA + qb * 8;
    }
    const __hip_bfloat16* pb[2];
#pragma unroll
    for (int j = 0; j < 2; j++)
        pb[j] = B + (long long)(n0 + 32 * wn + 16 * j + r16) * K + qb * 8;

    v4f acc[4][2];
#pragma unroll
    for (int i = 0; i < 4; i++)
#pragma unroll
        for (int j = 0; j < 2; j++) acc[i][j] = (v4f){0.f, 0.f, 0.f, 0.f};

    // prologue: load chunk 0
    v8bf af[4], bfr[2];
#pragma unroll
    for (int i = 0; i < 4; i++) af[i]  = *(const v8bf*)(pa[i]);
#pragma unroll
    for (int j = 0; j < 2; j++) bfr[j] = *(const v8bf*)(pb[j]);

    for (int k0 = 32; k0 < K; k0 += 32) {
        v8bf an[4], bn[2];
#pragma unroll
        for (int i = 0; i < 4; i++) an[i] = *(const v8bf*)(pa[i] + k0);
#pragma unroll
        for (int j = 0; j < 2; j++) bn[j] = *(const v8bf*)(pb[j] + k0);
#pragma unroll
        for (int i = 0; i < 4; i++)
#pragma unroll
            for (int j = 0; j < 2; j++)
                acc[i][j] = __builtin_amdgcn_mfma_f32_16x16x32_bf16(
                    af[i], bfr[j], acc[i][j], 0, 0, 0);
#pragma unroll
        for (int i = 0; i < 4; i++) af[i] = an[i];
#pragma unroll
        for (int j = 0; j < 2; j++) bfr[j] = bn[j];
    }
#pragma unroll
    for (int i = 0; i < 4; i++)
#pragma unroll
        for (int j = 0; j < 2; j++)
            acc[i][j] = __builtin_amdgcn_mfma_f32_16x16x32_bf16(
                af[i], bfr[j], acc[i][j], 0, 0, 0);

    float bv[2];
#pragma unroll
    for (int j = 0; j < 2; j++) bv[j] = bias[n0 + 32 * wn + 16 * j + r16];
    const int colbase = n0 + 32 * wn + r16;
#pragma unroll
    for (int i = 0; i < 4; i++) {
        int rowb = m0 + 64 * wm + 16 * i + qb * 4;
#pragma unroll
        for (int j = 0; j < 2; j++) {
            int col = colbase + 16 * j;
            float v[4];
#pragma unroll
            for (int r = 0; r < 4; r++) v[r] = acc[i][j][r] + bv[j];
            if (Ct && col >= ctcol0) {
                if (rowb + 3 < M) {
                    ushort4 o;
                    o.x = f2bfu(v[0]); o.y = f2bfu(v[1]);
                    o.z = f2bfu(v[2]); o.w = f2bfu(v[3]);
                    *(ushort4*)(Ct + ((long long)(rowb >> 10) << 20)
                                + (long long)(col - ctcol0) * 1024 + (rowb & 1023)) = o;
                }
            } else {
#pragma unroll
                for (int r = 0; r < 4; r++) {
                    int row = rowb + r;
                    if (row >= M) continue;
                    long long off = (long long)row * ldC + col;
                    float vv = v[r];
                    if (res)  vv += res[off];
                    if (relu) vv = fmaxf(vv, 0.f);
                    if (Cf) Cf[off] = vv;
                    if (Cb) ((unsigned short*)Cb)[off] = f2bfu(vv);
                }
            }
        }
    }
}

// ---------------------------------------------------------------------------
// MFMA softsign attention (unchanged from R3).
// ---------------------------------------------------------------------------
__global__ __launch_bounds__(256) void attn_mfma_k(
    const unsigned short* __restrict__ QKV,
    const unsigned short* __restrict__ Vt,
    unsigned short* __restrict__ O)
{
    __shared__ __align__(16) unsigned short lds[25600];
    const int t = threadIdx.x, w = t >> 6, l = t & 63;
    const int bh = blockIdx.y, b = bh >> 4, h = bh & 15;
    const int s0 = blockIdx.x << 7;
    const int r16 = l & 15, q4 = l >> 4;
    const long long qrow0 = (long long)(b << 10) + s0;
    const int hoff = h << 6;

#pragma unroll
    for (int mi = 0; mi < 2; mi++)
#pragma unroll
        for (int kk = 0; kk < 2; kk++) {
            const unsigned short* g = QKV + (qrow0 + 32 * w + 16 * mi + r16) * 3072
                                      + hoff + 32 * kk + q4 * 8;
            GLDS16(g, &lds[(w * 4 + mi * 2 + kk) * 512]);
        }
    __syncthreads();
    v8bf qf[2][2];
#pragma unroll
    for (int mi = 0; mi < 2; mi++)
#pragma unroll
        for (int kk = 0; kk < 2; kk++)
            qf[mi][kk] = *(const v8bf*)&lds[(w * 4 + mi * 2 + kk) * 512 + l * 8];

    v4f oacc[2][4];
#pragma unroll
    for (int i = 0; i < 2; i++)
#pragma unroll
        for (int j = 0; j < 4; j++) oacc[i][j] = (v4f){0.f, 0.f, 0.f, 0.f};

    for (int t0 = 0; t0 < 1024; t0 += 64) {
#pragma unroll
        for (int rr = 0; rr < 2; rr++) {
            int r = 2 * w + rr, kk = r >> 2, j = r & 3;
            const unsigned short* gk = QKV
                + ((long long)(b << 10) + t0 + 16 * j + r16) * 3072
                + 1024 + hoff + 32 * kk + q4 * 8;
            GLDS16(gk, &lds[8192 + r * 512]);
            const unsigned short* gv = Vt + ((long long)b << 20)
                + (long long)(hoff + 16 * j + r16) * 1024 + t0 + 32 * kk + q4 * 8;
            GLDS16(gv, &lds[12288 + r * 512]);
        }
        __syncthreads();

        v8bf kf[2][4];
#pragma unroll
        for (int kk = 0; kk < 2; kk++)
#pragma unroll
            for (int j = 0; j < 4; j++)
                kf[kk][j] = *(const v8bf*)&lds[8192 + (kk * 4 + j) * 512 + l * 8];
        v4f sc[2][4];
#pragma unroll
        for (int i = 0; i < 2; i++)
#pragma unroll
            for (int j = 0; j < 4; j++) sc[i][j] = (v4f){0.f, 0.f, 0.f, 0.f};
#pragma unroll
        for (int kk = 0; kk < 2; kk++)
#pragma unroll
            for (int mi = 0; mi < 2; mi++)
#pragma unroll
                for (int j = 0; j < 4; j++)
                    sc[mi][j] = __builtin_amdgcn_mfma_f32_16x16x32_bf16(
                        qf[mi][kk], kf[kk][j], sc[mi][j], 0, 0, 0);

#pragma unroll
        for (int mi = 0; mi < 2; mi++)
#pragma unroll
            for (int j = 0; j < 4; j++)
#pragma unroll
                for (int r = 0; r < 4; r++) {
                    float v = sc[mi][j][r] * 0.125f;
                    float p = v * __builtin_amdgcn_rcpf(1.0f + fabsf(v));
                    lds[16384 + (32 * w + 16 * mi + q4 * 4 + r) * 72 + 16 * j + r16] = f2bfu(p);
                }

        v8bf pf[2][2], vf[2][4];
#pragma unroll
        for (int mi = 0; mi < 2; mi++)
#pragma unroll
            for (int kk = 0; kk < 2; kk++)
                pf[mi][kk] = *(const v8bf*)&lds[16384 + (32 * w + 16 * mi + r16) * 72
                                                + 32 * kk + q4 * 8];
#pragma unroll
        for (int kk = 0; kk < 2; kk++)
#pragma unroll
            for (int j = 0; j < 4; j++)
                vf[kk][j] = *(const v8bf*)&lds[12288 + (kk * 4 + j) * 512 + l * 8];
#pragma unroll
        for (int kk = 0; kk < 2; kk++)
#pragma unroll
            for (int mi = 0; mi < 2; mi++)
#pragma unroll
                for (int j = 0; j < 4; j++)
                    oacc[mi][j] = __builtin_amdgcn_mfma_f32_16x16x32_bf16(
                        pf[mi][kk], vf[kk][j], oacc[mi][j], 0, 0, 0);
        __syncthreads();
    }

#pragma unroll
    for (int mi = 0; mi < 2; mi++)
#pragma unroll
        for (int j = 0; j < 4; j++)
#pragma unroll
            for (int r = 0; r < 4; r++)
                lds[(32 * w + 16 * mi + q4 * 4 + r) * 72 + 16 * j + r16] =
                    f2bfu(oacc[mi][j][r]);
    __syncthreads();
    {
        int row = t >> 1, ch = (t & 1) << 5;
#pragma unroll
        for (int i = 0; i < 4; i++) {
            v8us vv = *(const v8us*)&lds[row * 72 + ch + 8 * i];
            *(v8us*)(O + (qrow0 + row) * 1024 + hoff + ch + 8 * i) = vv;
        }
    }
}

// ---------------------------------------------------------------------------
__global__ __launch_bounds__(256) void layernorm_k(
    const float* __restrict__ x, const float* __restrict__ w,
    const float* __restrict__ b, unsigned short* __restrict__ y)
{
    int row = blockIdx.x;
    int t = threadIdx.x;
    float4 v = ((const float4*)(x + ((long long)row << 10)))[t];
    float s = v.x + v.y + v.z + v.w;
#pragma unroll
    for (int o = 32; o; o >>= 1) s += __shfl_down(s, o);
    __shared__ float red[4];
    __shared__ float red2[4];
    int wid = t >> 6, lane = t & 63;
    if (lane == 0) red[wid] = s;
    __syncthreads();
    float mean = (red[0] + red[1] + red[2] + red[3]) * (1.0f / 1024.0f);
    float dx = v.x - mean, dy = v.y - mean, dz = v.z - mean, dw = v.w - mean;
    float sq = dx * dx + dy * dy + dz * dz + dw * dw;
#pragma unroll
    for (int o = 32; o; o >>= 1) sq += __shfl_down(sq, o);
    if (lane == 0) red2[wid] = sq;
    __syncthreads();
    float var = (red2[0] + red2[1] + red2[2] + red2[3]) * (1.0f / 1023.0f);
    float inv = 1.0f / (sqrtf(var) + 1e-6f);
    float4 W  = ((const float4*)w)[t];
    float4 Bv = ((const float4*)b)[t];
    ushort4 o;
    o.x = f2bfu(W.x * (dx * inv) + Bv.x);
    o.y = f2bfu(W.y * (dy * inv) + Bv.y);
    o.z = f2bfu(W.z * (dz * inv) + Bv.z);
    o.w = f2bfu(W.w * (dw * inv) + Bv.w);
    ((ushort4*)(y + ((long long)row << 10)))[t] = o;
}

// ---------------------------------------------------------------------------
__global__ __launch_bounds__(256) void add_pos_k(float* __restrict__ h)
{
    int idx = blockIdx.x * 256 + threadIdx.x;
    int d = idx & 1023;
    int s = (idx >> 10) & 1023;
    int e = d & ~1;
    float div = expf(-9.210340371976184f * (float)e * (1.0f / 1024.0f));
    float arg = (float)s * div;
    float pe = (d & 1) ? cosf(arg) : sinf(arg);
    h[idx] += pe;
}

__global__ __launch_bounds__(256) void convert_k(
    const float* __restrict__ src, unsigned short* __restrict__ dst, int n4)
{
    int i = blockIdx.x * 256 + threadIdx.x;
    if (i >= n4) return;
    float4 v = ((const float4*)src)[i];
    ushort4 o;
    o.x = f2bfu(v.x); o.y = f2bfu(v.y); o.z = f2bfu(v.z); o.w = f2bfu(v.w);
    ((ushort4*)dst)[i] = o;
}

// One launch converts all 6 weight matrices of a layer into the contiguous
// bf16 region starting at wq_b (regions of 256K float4: q,k,v,o,f1lo,f1hi,f2lo,f2hi)
__global__ __launch_bounds__(256) void convert_layer_k(
    const float* __restrict__ q, const float* __restrict__ k,
    const float* __restrict__ v, const float* __restrict__ o,
    const float* __restrict__ f1, const float* __restrict__ f2,
    unsigned short* __restrict__ dst)
{
    int idx = blockIdx.x * 256 + threadIdx.x;
    int region = idx >> 18;
    int r = idx & 0x3FFFF;
    const float* src;
    switch (region) {
        case 0: src = q; break;
        case 1: src = k; break;
        case 2: src = v; break;
        case 3: src = o; break;
        case 4: src = f1; break;
        case 5: src = f1 + 1048576; break;
        case 6: src = f2; break;
        default: src = f2 + 1048576; break;
    }
    float4 vv = ((const float4*)src)[r];
    ushort4 ov;
    ov.x = f2bfu(vv.x); ov.y = f2bfu(vv.y); ov.z = f2bfu(vv.z); ov.w = f2bfu(vv.w);
    ((ushort4*)dst)[(region << 18) + r] = ov;
}

__global__ __launch_bounds__(256) void concat3_k(
    const float* __restrict__ a, const float* __restrict__ b,
    const float* __restrict__ c, float* __restrict__ o)
{
    int i = blockIdx.x * 256 + threadIdx.x;
    o[i] = (i < 1024) ? a[i] : ((i < 2048) ? b[i - 1024] : c[i - 2048]);
}

__global__ __launch_bounds__(256) void reorder_w_k(
    const float* __restrict__ src, unsigned short* __restrict__ dst, int OC, int IC)
{
    int idx = blockIdx.x * 256 + threadIdx.x;
    if (idx >= OC * IC * 3) return;
    int k  = idx % 3;
    int ic = (idx / 3) % IC;
    int oc = idx / (3 * IC);
    dst[(oc * 3 + k) * IC + ic] = f2bfu(src[idx]);
}

__global__ __launch_bounds__(256) void meanpool_k(
    const float* __restrict__ h, float* __restrict__ p)
{
    int g = blockIdx.x * 256 + threadIdx.x;
    int b = g >> 10, d = g & 1023;
    const float* base = h + ((long long)b << 20) + d;
    float s = 0.f;
    for (int i = 0; i < 1024; i++) s += base[(long long)i << 10];
    p[g] = s * (1.0f / 1024.0f);
}

__global__ __launch_bounds__(256) void fc_k(
    const float* __restrict__ p, const float* __restrict__ w,
    const float* __restrict__ fb, float* __restrict__ out)
{
    int b = blockIdx.x, t = threadIdx.x;
    float s = 0.f;
    for (int i = t; i < 1024; i += 256) s += p[(b << 10) + i] * w[i];
#pragma unroll
    for (int o = 32; o; o >>= 1) s += __shfl_down(s, o);
    __shared__ float red[4];
    if ((t & 63) == 0) red[t >> 6] = s;
    __syncthreads();
    if (t == 0) out[b] = red[0] + red[1] + red[2] + red[3] + fb[0];
}

// ---------------------------------------------------------------------------
extern "C" void kernel_launch(void* const* d_in, const int* in_sizes, int n_in,
                              void* d_out, int out_size, void* d_ws, size_t ws_size,
                              hipStream_t stream)
{
    const float* x    = (const float*)d_in[0];
    const float* c1w  = (const float*)d_in[1];
    const float* c1b  = (const float*)d_in[2];
    const float* c2w  = (const float*)d_in[3];
    const float* c2b  = (const float*)d_in[4];
    const float* lnAw = (const float*)d_in[5];
    const float* lnAb = (const float*)d_in[6];
    const float* qw   = (const float*)d_in[7];
    const float* qbi  = (const float*)d_in[8];
    const float* kw   = (const float*)d_in[9];
    const float* kbi  = (const float*)d_in[10];
    const float* vw   = (const float*)d_in[11];
    const float* vbi  = (const float*)d_in[12];
    const float* ow   = (const float*)d_in[13];
    const float* obi  = (const float*)d_in[14];
    const float* lnBw = (const float*)d_in[15];
    const float* lnBb = (const float*)d_in[16];
    const float* f1w  = (const float*)d_in[17];
    const float* f1b  = (const float*)d_in[18];
    const float* f2w  = (const float*)d_in[19];
    const float* f2b  = (const float*)d_in[20];
    const float* fcw  = (const float*)d_in[21];
    const float* fcb  = (const float*)d_in[22];
    float* out = (float*)d_out;

    float* ws = (float*)d_ws;
    typedef __hip_bfloat16 bf;
    typedef unsigned short us;
    float* h    = ws;                          // 4,194,304 f
    us* hn_b    = (us*)(ws + 4194304);         // 4M us
    us* qkv_b   = (us*)(ws + 6291456);         // [4096][3072] us
    us* ff_b    = qkv_b;                       // [4096][2048] us overlay
    us* wq_b    = (us*)(ws + 12582912);        // contiguous: q,k,v,o,f1,f2
    us* wo_b    = (us*)(ws + 14155776);
    us* wf1_b   = (us*)(ws + 14680064);
    us* wf2_b   = (us*)(ws + 15728640);
    us* xb      = (us*)(ws + 16777216);
    us* h1b     = (us*)(ws + 16912896);
    us* w1t_b   = (us*)(ws + 17963520);
    us* w2t_b   = (us*)(ws + 18012672);
    float* pooled = ws + 18799104;             // 4,096 f
    us* Vt      = (us*)(ws + 18803200);        // [4][1024 d][1024 t] us
    float* bqkv = ws + 20900352;               // 3,072 f

    convert_k<<<dim3(257), 256, 0, stream>>>(x, xb, 65792);
    reorder_w_k<<<dim3(384),  256, 0, stream>>>(c1w, w1t_b, 512, 64);
    reorder_w_k<<<dim3(6144), 256, 0, stream>>>(c2w, w2t_b, 1024, 512);

    // conv1: M=4104, N=512, K=192
    gemm_mfma_k<<<dim3(8, 33), 256, 0, stream>>>(
        (const bf*)xb, 1026, 1028LL * 64, 64, (const bf*)w1t_b,
        c1b, nullptr, nullptr, (bf*)h1b, nullptr, 0, 4104, 512, 192, 512, 0);
    // conv2: M=4096, N=1024, K=1536
    gemm_mfma_k<<<dim3(16, 32), 256, 0, stream>>>(
        (const bf*)h1b, 1024, 1026LL * 512, 512, (const bf*)w2t_b,
        c2b, nullptr, h, nullptr, nullptr, 0, 4096, 1024, 1536, 1024, 0);
    add_pos_k<<<dim3(16384), 256, 0, stream>>>(h);

    for (int l = 0; l < 4; l++) {
        long long wo  = (long long)l * 1048576;
        long long wo2 = (long long)l * 2097152;
        convert_layer_k<<<dim3(8192), 256, 0, stream>>>(
            qw + wo, kw + wo, vw + wo, ow + wo, f1w + wo2, f2w + wo2, wq_b);
        concat3_k<<<dim3(12), 256, 0, stream>>>(qbi + l * 1024, kbi + l * 1024,
                                                vbi + l * 1024, bqkv);

        layernorm_k<<<dim3(4096), 256, 0, stream>>>(h, lnAw + l * 1024, lnAb + l * 1024, hn_b);
        // fused QKV: N=3072; cols >=2048 (V) written transposed into Vt
        gemm_mfma_k<<<dim3(48, 32), 256, 0, stream>>>(
            (const bf*)hn_b, 1 << 30, 0, 1024, (const bf*)wq_b,
            bqkv, nullptr, nullptr, (bf*)qkv_b, Vt, 2048, 4096, 3072, 1024, 3072, 0);
        attn_mfma_k<<<dim3(8, 64), 256, 0, stream>>>(qkv_b, Vt, hn_b);
        gemm_mfma_k<<<dim3(16, 32), 256, 0, stream>>>(
            (const bf*)hn_b, 1 << 30, 0, 1024, (const bf*)wo_b,
            obi + l * 1024, h, h, nullptr, nullptr, 0, 4096, 1024, 1024, 1024, 0);
        layernorm_k<<<dim3(4096), 256, 0, stream>>>(h, lnBw + l * 1024, lnBb + l * 1024, hn_b);
        gemm_mfma_k<<<dim3(32, 32), 256, 0, stream>>>(
            (const bf*)hn_b, 1 << 30, 0, 1024, (const bf*)wf1_b,
            f1b + l * 2048, nullptr, nullptr, (bf*)ff_b, nullptr, 0, 4096, 2048, 1024, 2048, 1);
        gemm_mfma_k<<<dim3(16, 32), 256, 0, stream>>>(
            (const bf*)ff_b, 1 << 30, 0, 2048, (const bf*)wf2_b,
            f2b + l * 1024, h, h, nullptr, nullptr, 0, 4096, 1024, 2048, 1024, 0);
    }

    meanpool_k<<<dim3(16), 256, 0, stream>>>(h, pooled);
    fc_k<<<dim3(4), 256, 0, stream>>>(pooled, fcw, fcb, out);
}

// Round 7
// 1180.375 us; speedup vs baseline: 1.7499x; 1.7499x over previous
//
#include <hip/hip_runtime.h>
#include <hip/hip_bf16.h>
#include <math.h>

// ---------------------------------------------------------------------------
// helpers
// ---------------------------------------------------------------------------
typedef __bf16 v8bf __attribute__((ext_vector_type(8)));
typedef float  v4f  __attribute__((ext_vector_type(4)));
typedef unsigned short v8us __attribute__((ext_vector_type(8)));

__device__ __forceinline__ unsigned short f2bfu(float f) {
    unsigned u = __builtin_bit_cast(unsigned, f);
    unsigned r = (u + 0x7fffu + ((u >> 16) & 1u)) >> 16;
    return (unsigned short)r;
}
__device__ __forceinline__ float bf2f(unsigned short u) {
    unsigned x = ((unsigned)u) << 16;
    return __builtin_bit_cast(float, x);
}

// fragment-swizzled element address: matrix [rows][K cols] stored so that a
// wave's 16x32 MFMA fragment is contiguous: sw(r,k) =
//   tile(r>>4, k>>5) * 512 + lane((k>>3)&3, r&15) * 8 + (k&7)
__device__ __forceinline__ long long swidx(int r, int k, int kt /*=K>>5*/) {
    return ((long long)((r >> 4) * kt + (k >> 5)) << 9)
         + (((k >> 3) & 3) << 7) + ((r & 15) << 3) + (k & 7);
}

#define GLDS16(g, s)                                                        \
    __builtin_amdgcn_global_load_lds(                                       \
        (const __attribute__((address_space(1))) void*)(g),                 \
        (__attribute__((address_space(3))) void*)(s), 16, 0, 0)

// ---------------------------------------------------------------------------
// SWIZZLED register-direct bf16 MFMA GEMM (no LDS, no barriers).
// A (M x K) and B (N x K) are in fragment-swizzled layout (see swidx).
// Per wave: 64x32 output, BK=64 register-double-buffered: 12 fully-coalesced
// 1KB loads + 16 MFMAs per iter; compiler tracks per-register deps so load
// latency overlaps MFMA across independent waves (no vmcnt(0) drain).
// Outputs: Cf (fp32,+res row-major) | Cb (bf16 row-major) | Csw (bf16
// swizzled for the next GEMM, K_consumer = N) ; cols >= ctcol0 (Ct!=null)
// go transposed to Ct (attention V^T). M,N,K multiples of 128/64/64.
// ---------------------------------------------------------------------------
__global__ __launch_bounds__(256) void gemm_sw_k(
    const unsigned short* __restrict__ Asw,
    const unsigned short* __restrict__ Bsw,
    const float* __restrict__ bias,
    const float* __restrict__ res,
    float* __restrict__ Cf,
    unsigned short* __restrict__ Cb,
    unsigned short* __restrict__ Csw,
    unsigned short* __restrict__ Ct, int ctcol0,
    int M, int N, int K, int ldC, int relu)
{
    const int t = threadIdx.x;
    const int w = t >> 6;
    const int l = t & 63;

    int bx = blockIdx.x, by = blockIdx.y;
    {
        int nbx = gridDim.x;
        int nb  = nbx * gridDim.y;
        if ((nb & 7) == 0) {
            int bid = by * nbx + bx;
            int nid = (bid & 7) * (nb >> 3) + (bid >> 3);
            by = nid / nbx;
            bx = nid - by * nbx;
        }
    }
    const int m0 = by * 128;
    const int n0 = bx * 64;
    const int r16 = l & 15;
    const int qb  = l >> 4;
    const int wm = w >> 1, wn = w & 1;
    const int kt = K >> 5;

    // fragment base pointers: contiguous 16B per lane
    const unsigned short* pa[4];
#pragma unroll
    for (int i = 0; i < 4; i++)
        pa[i] = Asw + ((long long)(((m0 >> 4) + 4 * wm + i) * kt) << 9) + l * 8;
    const unsigned short* pb[2];
#pragma unroll
    for (int j = 0; j < 2; j++)
        pb[j] = Bsw + ((long long)(((((n0 + 32 * wn) >> 4) + j)) * kt) << 9) + l * 8;

    v4f acc[4][2];
#pragma unroll
    for (int i = 0; i < 4; i++)
#pragma unroll
        for (int j = 0; j < 2; j++) acc[i][j] = (v4f){0.f, 0.f, 0.f, 0.f};

    // prologue: chunks 0,1
    v8bf a0[4], a1[4], b0[2], b1[2];
#pragma unroll
    for (int i = 0; i < 4; i++) {
        a0[i] = *(const v8bf*)(pa[i]);
        a1[i] = *(const v8bf*)(pa[i] + 512);
    }
#pragma unroll
    for (int j = 0; j < 2; j++) {
        b0[j] = *(const v8bf*)(pb[j]);
        b1[j] = *(const v8bf*)(pb[j] + 512);
    }

    for (int kc = 2; kc < kt; kc += 2) {
        v8bf na0[4], na1[4], nb0[2], nb1[2];
#pragma unroll
        for (int i = 0; i < 4; i++) {
            na0[i] = *(const v8bf*)(pa[i] + (long long)kc * 512);
            na1[i] = *(const v8bf*)(pa[i] + (long long)(kc + 1) * 512);
        }
#pragma unroll
        for (int j = 0; j < 2; j++) {
            nb0[j] = *(const v8bf*)(pb[j] + (long long)kc * 512);
            nb1[j] = *(const v8bf*)(pb[j] + (long long)(kc + 1) * 512);
        }
#pragma unroll
        for (int i = 0; i < 4; i++)
#pragma unroll
            for (int j = 0; j < 2; j++)
                acc[i][j] = __builtin_amdgcn_mfma_f32_16x16x32_bf16(
                    a0[i], b0[j], acc[i][j], 0, 0, 0);
#pragma unroll
        for (int i = 0; i < 4; i++)
#pragma unroll
            for (int j = 0; j < 2; j++)
                acc[i][j] = __builtin_amdgcn_mfma_f32_16x16x32_bf16(
                    a1[i], b1[j], acc[i][j], 0, 0, 0);
#pragma unroll
        for (int i = 0; i < 4; i++) { a0[i] = na0[i]; a1[i] = na1[i]; }
#pragma unroll
        for (int j = 0; j < 2; j++) { b0[j] = nb0[j]; b1[j] = nb1[j]; }
    }
#pragma unroll
    for (int i = 0; i < 4; i++)
#pragma unroll
        for (int j = 0; j < 2; j++)
            acc[i][j] = __builtin_amdgcn_mfma_f32_16x16x32_bf16(
                a0[i], b0[j], acc[i][j], 0, 0, 0);
#pragma unroll
    for (int i = 0; i < 4; i++)
#pragma unroll
        for (int j = 0; j < 2; j++)
            acc[i][j] = __builtin_amdgcn_mfma_f32_16x16x32_bf16(
                a1[i], b1[j], acc[i][j], 0, 0, 0);

    float bv[2];
#pragma unroll
    for (int j = 0; j < 2; j++) bv[j] = bias[n0 + 32 * wn + 16 * j + r16];
    const int colbase = n0 + 32 * wn + r16;
    const int nt = N >> 5;
#pragma unroll
    for (int i = 0; i < 4; i++) {
        int rowb = m0 + 64 * wm + 16 * i + qb * 4;
#pragma unroll
        for (int j = 0; j < 2; j++) {
            int col = colbase + 16 * j;
            float v[4];
#pragma unroll
            for (int r = 0; r < 4; r++) v[r] = acc[i][j][r] + bv[j];
            if (Ct && col >= ctcol0) {
                ushort4 o;
                o.x = f2bfu(v[0]); o.y = f2bfu(v[1]);
                o.z = f2bfu(v[2]); o.w = f2bfu(v[3]);
                *(ushort4*)(Ct + ((long long)(rowb >> 10) << 20)
                            + (long long)(col - ctcol0) * 1024 + (rowb & 1023)) = o;
            } else if (Csw) {
#pragma unroll
                for (int r = 0; r < 4; r++) {
                    int row = rowb + r;
                    float vv = v[r];
                    if (relu) vv = fmaxf(vv, 0.f);
                    Csw[swidx(row, col, nt)] = f2bfu(vv);
                }
            } else {
#pragma unroll
                for (int r = 0; r < 4; r++) {
                    int row = rowb + r;
                    long long off = (long long)row * ldC + col;
                    float vv = v[r];
                    if (res)  vv += res[off];
                    if (relu) vv = fmaxf(vv, 0.f);
                    if (Cf) Cf[off] = vv;
                    if (Cb) Cb[off] = f2bfu(vv);
                }
            }
        }
    }
}

// ---------------------------------------------------------------------------
// LDS-staged GEMM (R5) — kept for the conv frontend (row-remapped A).
// ---------------------------------------------------------------------------
__global__ __launch_bounds__(256) void gemm_mfma_k(
    const __hip_bfloat16* __restrict__ A, int rpbA, long long bstrideA, int ldA,
    const __hip_bfloat16* __restrict__ B,
    const float* __restrict__ bias,
    const float* __restrict__ res,
    float* __restrict__ Cf,
    __hip_bfloat16* __restrict__ Cb,
    int M, int N, int K, int ldC, int relu)
{
    __shared__ __align__(16) __hip_bfloat16 As[2][8][64][8];
    __shared__ __align__(16) __hip_bfloat16 Bs[2][4][64][8];
    const int t  = threadIdx.x;
    const int w  = t >> 6;
    const int l  = t & 63;
    const int m0 = blockIdx.y * 128;
    const int n0 = blockIdx.x * 64;
    const int r16 = l & 15;
    const int qb  = l >> 4;
    const int wm = w >> 1, wn = w & 1;

    const __hip_bfloat16* gA[2];
#pragma unroll
    for (int tt = 0; tt < 2; tt++) {
        int arow = m0 + 16 * (2 * w + tt) + r16;
        gA[tt] = A + (long long)(arow / rpbA) * bstrideA
                   + (long long)(arow % rpbA) * ldA + qb * 8;
    }
    const __hip_bfloat16* gB = B + (long long)(n0 + 16 * w + r16) * K + qb * 8;

    v4f acc[4][2];
#pragma unroll
    for (int i = 0; i < 4; i++)
#pragma unroll
        for (int j = 0; j < 2; j++) acc[i][j] = (v4f){0.f, 0.f, 0.f, 0.f};

    GLDS16(gA[0], &As[0][2 * w + 0][0][0]);
    GLDS16(gA[1], &As[0][2 * w + 1][0][0]);
    GLDS16(gB,    &Bs[0][w][0][0]);
    __syncthreads();

    int cur = 0;
    for (int k0 = 32; k0 < K; k0 += 32) {
        v8bf af[4], bfr[2];
#pragma unroll
        for (int i = 0; i < 4; i++) af[i]  = *(const v8bf*)(&As[cur][4 * wm + i][l][0]);
#pragma unroll
        for (int j = 0; j < 2; j++) bfr[j] = *(const v8bf*)(&Bs[cur][2 * wn + j][l][0]);
        GLDS16(gA[0] + k0, &As[cur ^ 1][2 * w + 0][0][0]);
        GLDS16(gA[1] + k0, &As[cur ^ 1][2 * w + 1][0][0]);
        GLDS16(gB + k0,    &Bs[cur ^ 1][w][0][0]);
#pragma unroll
        for (int i = 0; i < 4; i++)
#pragma unroll
            for (int j = 0; j < 2; j++)
                acc[i][j] = __builtin_amdgcn_mfma_f32_16x16x32_bf16(
                    af[i], bfr[j], acc[i][j], 0, 0, 0);
        __syncthreads();
        cur ^= 1;
    }
    {
        v8bf af[4], bfr[2];
#pragma unroll
        for (int i = 0; i < 4; i++) af[i]  = *(const v8bf*)(&As[cur][4 * wm + i][l][0]);
#pragma unroll
        for (int j = 0; j < 2; j++) bfr[j] = *(const v8bf*)(&Bs[cur][2 * wn + j][l][0]);
#pragma unroll
        for (int i = 0; i < 4; i++)
#pragma unroll
            for (int j = 0; j < 2; j++)
                acc[i][j] = __builtin_amdgcn_mfma_f32_16x16x32_bf16(
                    af[i], bfr[j], acc[i][j], 0, 0, 0);
    }

    float bv[2];
#pragma unroll
    for (int j = 0; j < 2; j++) bv[j] = bias[n0 + 32 * wn + 16 * j + r16];
    const int colbase = n0 + 32 * wn + r16;
#pragma unroll
    for (int i = 0; i < 4; i++) {
        int rowb = m0 + 64 * wm + 16 * i + qb * 4;
#pragma unroll
        for (int j = 0; j < 2; j++) {
            int col = colbase + 16 * j;
#pragma unroll
            for (int r = 0; r < 4; r++) {
                int row = rowb + r;
                if (row >= M) continue;
                long long off = (long long)row * ldC + col;
                float vv = acc[i][j][r] + bv[j];
                if (res)  vv += res[off];
                if (relu) vv = fmaxf(vv, 0.f);
                if (Cf) Cf[off] = vv;
                if (Cb) ((unsigned short*)Cb)[off] = f2bfu(vv);
            }
        }
    }
}

// ---------------------------------------------------------------------------
// MFMA softsign attention. Output written in SWIZZLED layout (K=1024 -> 32).
// ---------------------------------------------------------------------------
__global__ __launch_bounds__(256) void attn_mfma_k(
    const unsigned short* __restrict__ QKV,
    const unsigned short* __restrict__ Vt,
    unsigned short* __restrict__ Osw)
{
    __shared__ __align__(16) unsigned short lds[25600];
    const int t = threadIdx.x, w = t >> 6, l = t & 63;
    const int bh = blockIdx.y, b = bh >> 4, h = bh & 15;
    const int s0 = blockIdx.x << 7;
    const int r16 = l & 15, q4 = l >> 4;
    const long long qrow0 = (long long)(b << 10) + s0;
    const int hoff = h << 6;

#pragma unroll
    for (int mi = 0; mi < 2; mi++)
#pragma unroll
        for (int kk = 0; kk < 2; kk++) {
            const unsigned short* g = QKV + (qrow0 + 32 * w + 16 * mi + r16) * 3072
                                      + hoff + 32 * kk + q4 * 8;
            GLDS16(g, &lds[(w * 4 + mi * 2 + kk) * 512]);
        }
    __syncthreads();
    v8bf qf[2][2];
#pragma unroll
    for (int mi = 0; mi < 2; mi++)
#pragma unroll
        for (int kk = 0; kk < 2; kk++)
            qf[mi][kk] = *(const v8bf*)&lds[(w * 4 + mi * 2 + kk) * 512 + l * 8];

    v4f oacc[2][4];
#pragma unroll
    for (int i = 0; i < 2; i++)
#pragma unroll
        for (int j = 0; j < 4; j++) oacc[i][j] = (v4f){0.f, 0.f, 0.f, 0.f};

    for (int t0 = 0; t0 < 1024; t0 += 64) {
#pragma unroll
        for (int rr = 0; rr < 2; rr++) {
            int r = 2 * w + rr, kk = r >> 2, j = r & 3;
            const unsigned short* gk = QKV
                + ((long long)(b << 10) + t0 + 16 * j + r16) * 3072
                + 1024 + hoff + 32 * kk + q4 * 8;
            GLDS16(gk, &lds[8192 + r * 512]);
            const unsigned short* gv = Vt + ((long long)b << 20)
                + (long long)(hoff + 16 * j + r16) * 1024 + t0 + 32 * kk + q4 * 8;
            GLDS16(gv, &lds[12288 + r * 512]);
        }
        __syncthreads();

        v8bf kf[2][4];
#pragma unroll
        for (int kk = 0; kk < 2; kk++)
#pragma unroll
            for (int j = 0; j < 4; j++)
                kf[kk][j] = *(const v8bf*)&lds[8192 + (kk * 4 + j) * 512 + l * 8];
        v4f sc[2][4];
#pragma unroll
        for (int i = 0; i < 2; i++)
#pragma unroll
            for (int j = 0; j < 4; j++) sc[i][j] = (v4f){0.f, 0.f, 0.f, 0.f};
#pragma unroll
        for (int kk = 0; kk < 2; kk++)
#pragma unroll
            for (int mi = 0; mi < 2; mi++)
#pragma unroll
                for (int j = 0; j < 4; j++)
                    sc[mi][j] = __builtin_amdgcn_mfma_f32_16x16x32_bf16(
                        qf[mi][kk], kf[kk][j], sc[mi][j], 0, 0, 0);

#pragma unroll
        for (int mi = 0; mi < 2; mi++)
#pragma unroll
            for (int j = 0; j < 4; j++)
#pragma unroll
                for (int r = 0; r < 4; r++) {
                    float v = sc[mi][j][r] * 0.125f;
                    float p = v * __builtin_amdgcn_rcpf(1.0f + fabsf(v));
                    lds[16384 + (32 * w + 16 * mi + q4 * 4 + r) * 72 + 16 * j + r16] = f2bfu(p);
                }

        v8bf pf[2][2], vf[2][4];
#pragma unroll
        for (int mi = 0; mi < 2; mi++)
#pragma unroll
            for (int kk = 0; kk < 2; kk++)
                pf[mi][kk] = *(const v8bf*)&lds[16384 + (32 * w + 16 * mi + r16) * 72
                                                + 32 * kk + q4 * 8];
#pragma unroll
        for (int kk = 0; kk < 2; kk++)
#pragma unroll
            for (int j = 0; j < 4; j++)
                vf[kk][j] = *(const v8bf*)&lds[12288 + (kk * 4 + j) * 512 + l * 8];
#pragma unroll
        for (int kk = 0; kk < 2; kk++)
#pragma unroll
            for (int mi = 0; mi < 2; mi++)
#pragma unroll
                for (int j = 0; j < 4; j++)
                    oacc[mi][j] = __builtin_amdgcn_mfma_f32_16x16x32_bf16(
                        pf[mi][kk], vf[kk][j], oacc[mi][j], 0, 0, 0);
        __syncthreads();
    }

#pragma unroll
    for (int mi = 0; mi < 2; mi++)
#pragma unroll
        for (int j = 0; j < 4; j++)
#pragma unroll
            for (int r = 0; r < 4; r++)
                lds[(32 * w + 16 * mi + q4 * 4 + r) * 72 + 16 * j + r16] =
                    f2bfu(oacc[mi][j][r]);
    __syncthreads();
    {
        int row = t >> 1, ch = (t & 1) << 5;
        int grow = (int)qrow0 + row;
#pragma unroll
        for (int i = 0; i < 4; i++) {
            int c0 = hoff + ch + 8 * i;
            v8us vv = *(const v8us*)&lds[row * 72 + ch + 8 * i];
            *(v8us*)(Osw + swidx(grow, c0, 32)) = vv;
        }
    }
}

// ---------------------------------------------------------------------------
// LayerNorm (torch-style), output bf16 in SWIZZLED layout (K=1024).
// ---------------------------------------------------------------------------
__global__ __launch_bounds__(256) void layernorm_k(
    const float* __restrict__ x, const float* __restrict__ w,
    const float* __restrict__ b, unsigned short* __restrict__ ysw)
{
    int row = blockIdx.x;
    int t = threadIdx.x;
    float4 v = ((const float4*)(x + ((long long)row << 10)))[t];
    float s = v.x + v.y + v.z + v.w;
#pragma unroll
    for (int o = 32; o; o >>= 1) s += __shfl_down(s, o);
    __shared__ float red[4];
    __shared__ float red2[4];
    int wid = t >> 6, lane = t & 63;
    if (lane == 0) red[wid] = s;
    __syncthreads();
    float mean = (red[0] + red[1] + red[2] + red[3]) * (1.0f / 1024.0f);
    float dx = v.x - mean, dy = v.y - mean, dz = v.z - mean, dw = v.w - mean;
    float sq = dx * dx + dy * dy + dz * dz + dw * dw;
#pragma unroll
    for (int o = 32; o; o >>= 1) sq += __shfl_down(sq, o);
    if (lane == 0) red2[wid] = sq;
    __syncthreads();
    float var = (red2[0] + red2[1] + red2[2] + red2[3]) * (1.0f / 1023.0f);
    float inv = 1.0f / (sqrtf(var) + 1e-6f);
    float4 W  = ((const float4*)w)[t];
    float4 Bv = ((const float4*)b)[t];
    ushort4 o;
    o.x = f2bfu(W.x * (dx * inv) + Bv.x);
    o.y = f2bfu(W.y * (dy * inv) + Bv.y);
    o.z = f2bfu(W.z * (dz * inv) + Bv.z);
    o.w = f2bfu(W.w * (dw * inv) + Bv.w);
    int c0 = t << 2;
    *(ushort4*)(ysw + swidx(row, c0, 32)) = o;
}

// ---------------------------------------------------------------------------
__global__ __launch_bounds__(256) void add_pos_k(float* __restrict__ h)
{
    int idx = blockIdx.x * 256 + threadIdx.x;
    int d = idx & 1023;
    int s = (idx >> 10) & 1023;
    int e = d & ~1;
    float div = expf(-9.210340371976184f * (float)e * (1.0f / 1024.0f));
    float arg = (float)s * div;
    float pe = (d & 1) ? cosf(arg) : sinf(arg);
    h[idx] += pe;
}

__global__ __launch_bounds__(256) void convert_k(
    const float* __restrict__ src, unsigned short* __restrict__ dst, int n4)
{
    int i = blockIdx.x * 256 + threadIdx.x;
    if (i >= n4) return;
    float4 v = ((const float4*)src)[i];
    ushort4 o;
    o.x = f2bfu(v.x); o.y = f2bfu(v.y); o.z = f2bfu(v.z); o.w = f2bfu(v.w);
    ((ushort4*)dst)[i] = o;
}

// Layer weights fp32 row-major -> bf16 SWIZZLED, all 6 matrices, one launch.
// dst layout (us): q,k,v,o (1M each), f1 (2M), f2 (2M) — contiguous.
__global__ __launch_bounds__(256) void convert_layer_sw_k(
    const float* __restrict__ q, const float* __restrict__ k,
    const float* __restrict__ v, const float* __restrict__ o,
    const float* __restrict__ f1, const float* __restrict__ f2,
    unsigned short* __restrict__ dst)
{
    int idx = blockIdx.x * 256 + threadIdx.x;   // float4 index, [0, 2M)
    const float* src;
    unsigned short* db;
    int Ksh, rf;
    if (idx < 0x100000) {
        int region = idx >> 18;
        rf = idx & 0x3FFFF;
        src = (region == 0) ? q : (region == 1) ? k : (region == 2) ? v : o;
        db = dst + ((long long)region << 20);
        Ksh = 10;
    } else if (idx < 0x180000) {
        rf = idx - 0x100000; src = f1; db = dst + (4LL << 20); Ksh = 10;
    } else {
        rf = idx - 0x180000; src = f2; db = dst + (6LL << 20); Ksh = 11;
    }
    float4 vv = ((const float4*)src)[rf];
    int flatf = rf << 2;
    int n  = flatf >> Ksh;
    int k0 = flatf & ((1 << Ksh) - 1);
    ushort4 ov;
    ov.x = f2bfu(vv.x); ov.y = f2bfu(vv.y); ov.z = f2bfu(vv.z); ov.w = f2bfu(vv.w);
    *(ushort4*)(db + swidx(n, k0, 1 << (Ksh - 5))) = ov;
}

__global__ __launch_bounds__(256) void concat3_k(
    const float* __restrict__ a, const float* __restrict__ b,
    const float* __restrict__ c, float* __restrict__ o)
{
    int i = blockIdx.x * 256 + threadIdx.x;
    o[i] = (i < 1024) ? a[i] : ((i < 2048) ? b[i - 1024] : c[i - 2048]);
}

__global__ __launch_bounds__(256) void reorder_w_k(
    const float* __restrict__ src, unsigned short* __restrict__ dst, int OC, int IC)
{
    int idx = blockIdx.x * 256 + threadIdx.x;
    if (idx >= OC * IC * 3) return;
    int k  = idx % 3;
    int ic = (idx / 3) % IC;
    int oc = idx / (3 * IC);
    dst[(oc * 3 + k) * IC + ic] = f2bfu(src[idx]);
}

__global__ __launch_bounds__(256) void meanpool_k(
    const float* __restrict__ h, float* __restrict__ p)
{
    int g = blockIdx.x * 256 + threadIdx.x;
    int b = g >> 10, d = g & 1023;
    const float* base = h + ((long long)b << 20) + d;
    float s = 0.f;
    for (int i = 0; i < 1024; i++) s += base[(long long)i << 10];
    p[g] = s * (1.0f / 1024.0f);
}

__global__ __launch_bounds__(256) void fc_k(
    const float* __restrict__ p, const float* __restrict__ w,
    const float* __restrict__ fb, float* __restrict__ out)
{
    int b = blockIdx.x, t = threadIdx.x;
    float s = 0.f;
    for (int i = t; i < 1024; i += 256) s += p[(b << 10) + i] * w[i];
#pragma unroll
    for (int o = 32; o; o >>= 1) s += __shfl_down(s, o);
    __shared__ float red[4];
    if ((t & 63) == 0) red[t >> 6] = s;
    __syncthreads();
    if (t == 0) out[b] = red[0] + red[1] + red[2] + red[3] + fb[0];
}

// ---------------------------------------------------------------------------
extern "C" void kernel_launch(void* const* d_in, const int* in_sizes, int n_in,
                              void* d_out, int out_size, void* d_ws, size_t ws_size,
                              hipStream_t stream)
{
    const float* x    = (const float*)d_in[0];
    const float* c1w  = (const float*)d_in[1];
    const float* c1b  = (const float*)d_in[2];
    const float* c2w  = (const float*)d_in[3];
    const float* c2b  = (const float*)d_in[4];
    const float* lnAw = (const float*)d_in[5];
    const float* lnAb = (const float*)d_in[6];
    const float* qw   = (const float*)d_in[7];
    const float* qbi  = (const float*)d_in[8];
    const float* kw   = (const float*)d_in[9];
    const float* kbi  = (const float*)d_in[10];
    const float* vw   = (const float*)d_in[11];
    const float* vbi  = (const float*)d_in[12];
    const float* ow   = (const float*)d_in[13];
    const float* obi  = (const float*)d_in[14];
    const float* lnBw = (const float*)d_in[15];
    const float* lnBb = (const float*)d_in[16];
    const float* f1w  = (const float*)d_in[17];
    const float* f1b  = (const float*)d_in[18];
    const float* f2w  = (const float*)d_in[19];
    const float* f2b  = (const float*)d_in[20];
    const float* fcw  = (const float*)d_in[21];
    const float* fcb  = (const float*)d_in[22];
    float* out = (float*)d_out;

    float* ws = (float*)d_ws;
    typedef __hip_bfloat16 bf;
    typedef unsigned short us;
    float* h    = ws;                          // 4,194,304 f
    us* hn_b    = (us*)(ws + 4194304);         // 4M us (swizzled activations)
    us* qkv_b   = (us*)(ws + 6291456);         // [4096][3072] us row-major
    us* ff_b    = qkv_b;                       // [4096][2048] swizzled overlay
    us* wq_b    = (us*)(ws + 12582912);        // swizzled: q,k,v,o,f1,f2
    us* wo_b    = (us*)(ws + 14155776);
    us* wf1_b   = (us*)(ws + 14680064);
    us* wf2_b   = (us*)(ws + 15728640);
    us* xb      = (us*)(ws + 16777216);
    us* h1b     = (us*)(ws + 16912896);
    us* w1t_b   = (us*)(ws + 17963520);
    us* w2t_b   = (us*)(ws + 18012672);
    float* pooled = ws + 18799104;             // 4,096 f
    us* Vt      = (us*)(ws + 18803200);        // [4][1024 d][1024 t] us
    float* bqkv = ws + 20900352;               // 3,072 f

    convert_k<<<dim3(257), 256, 0, stream>>>(x, xb, 65792);
    reorder_w_k<<<dim3(384),  256, 0, stream>>>(c1w, w1t_b, 512, 64);
    reorder_w_k<<<dim3(6144), 256, 0, stream>>>(c2w, w2t_b, 1024, 512);

    // conv1: M=4104, N=512, K=192 (LDS-staged kernel, row-remapped A)
    gemm_mfma_k<<<dim3(8, 33), 256, 0, stream>>>(
        (const bf*)xb, 1026, 1028LL * 64, 64, (const bf*)w1t_b,
        c1b, nullptr, nullptr, (bf*)h1b, 4104, 512, 192, 512, 0);
    // conv2: M=4096, N=1024, K=1536
    gemm_mfma_k<<<dim3(16, 32), 256, 0, stream>>>(
        (const bf*)h1b, 1024, 1026LL * 512, 512, (const bf*)w2t_b,
        c2b, nullptr, h, nullptr, 4096, 1024, 1536, 1024, 0);
    add_pos_k<<<dim3(16384), 256, 0, stream>>>(h);

    for (int l = 0; l < 4; l++) {
        long long wo  = (long long)l * 1048576;
        long long wo2 = (long long)l * 2097152;
        convert_layer_sw_k<<<dim3(8192), 256, 0, stream>>>(
            qw + wo, kw + wo, vw + wo, ow + wo, f1w + wo2, f2w + wo2, wq_b);
        concat3_k<<<dim3(12), 256, 0, stream>>>(qbi + l * 1024, kbi + l * 1024,
                                                vbi + l * 1024, bqkv);

        layernorm_k<<<dim3(4096), 256, 0, stream>>>(h, lnAw + l * 1024, lnAb + l * 1024, hn_b);
        // fused QKV: N=3072; Q,K row-major to qkv_b; V transposed to Vt
        gemm_sw_k<<<dim3(48, 32), 256, 0, stream>>>(
            hn_b, wq_b, bqkv, nullptr, nullptr, qkv_b, nullptr, Vt, 2048,
            4096, 3072, 1024, 3072, 0);
        attn_mfma_k<<<dim3(8, 64), 256, 0, stream>>>(qkv_b, Vt, hn_b);
        // O-proj: out fp32 h += res
        gemm_sw_k<<<dim3(16, 32), 256, 0, stream>>>(
            hn_b, wo_b, obi + l * 1024, h, h, nullptr, nullptr, nullptr, 0,
            4096, 1024, 1024, 1024, 0);
        layernorm_k<<<dim3(4096), 256, 0, stream>>>(h, lnBw + l * 1024, lnBb + l * 1024, hn_b);
        // FF1: out swizzled bf16 (+relu)
        gemm_sw_k<<<dim3(32, 32), 256, 0, stream>>>(
            hn_b, wf1_b, f1b + l * 2048, nullptr, nullptr, nullptr, ff_b, nullptr, 0,
            4096, 2048, 1024, 2048, 1);
        // FF2: out fp32 h += res
        gemm_sw_k<<<dim3(16, 32), 256, 0, stream>>>(
            ff_b, wf2_b, f2b + l * 1024, h, h, nullptr, nullptr, nullptr, 0,
            4096, 1024, 2048, 1024, 0);
    }

    meanpool_k<<<dim3(16), 256, 0, stream>>>(h, pooled);
    fc_k<<<dim3(4), 256, 0, stream>>>(pooled, fcw, fcb, out);
}